// Round 4
// baseline (567.220 us; speedup 1.0000x reference)
//
#include <hip/hip_runtime.h>
#include <hip/hip_bf16.h>

// Kalman recurrence, exact chunked parallelization. Round 4: f16 MFMA GEMMs.
//   x[k+1] = M x[k] + L y[:,k],  M = A - L H,  yhat[:,k] = H x[k], x[0]=0
// Chunk T=16:  yhat[cT+t] = F_t x_c + sum_{s<t} K_{t-1-s} y[cT+s]
//   F_t = H M^t, K_d = H M^d L, v_c = sum_t M^{15-t} L y[cT+t]
//   x_{c+1} = P x_c + v_c, P = M^16.  3-level fp32 scan over C=16384 chunks.
// GEMMs in f16 (fp32 accum), k-contiguous layouts, no LDS (operands L2/L3-hot):
//   C[nn][mm] = sum_k Zh[nn][k] * Bh[mm][k]  via mfma_f32_16x16x32_f16.

#define NSTEP 262144
#define T 16
#define CCH (NSTEP / T)          // 16384 chunks
#define KDIM (64 + 32 * T)       // 576
#define MOUT (32 * T)            // 512
#define NBLK 128                 // scan blocks
#define SB (CCH / NBLK)          // 128 chunks per scan block

typedef _Float16 f16;
typedef _Float16 f16x8 __attribute__((ext_vector_type(8)));
typedef float f32x4 __attribute__((ext_vector_type(4)));

// ---- workspace layout (float units; f16 arrays use half as many floats) ----
#define OFF_ZH 0                          // Zh: f16 [CCH][576]  k-contiguous
#define SZ_ZH  (CCH * KDIM / 2)
#define OFF_VT (OFF_ZH + SZ_ZH)           // VT: f32 [CCH][64]  chunk summaries
#define SZ_VT  (CCH * 64)
#define OFF_MP (OFF_VT + SZ_VT)           // M powers f32: {M,M2,M4,M8,M16,M2048}
#define SZ_MP  (6 * 4096)
#define OFF_BOH (OFF_MP + SZ_MP)          // BOh: f16 [512][576] rows r=i*16+t
#define SZ_BOH (MOUT * KDIM / 2)
#define OFF_GCH (OFF_BOH + SZ_BOH)        // GCh: f16 [64][512]
#define SZ_GCH (64 * 512 / 2)
#define OFF_W  (OFF_GCH + SZ_GCH)         // [128][64] scan-block summaries
#define OFF_XB (OFF_W + NBLK * 64)        // [128][64] block start states

// ---- pack: Zh[c][64 + t*32 + i] = (f16) y[i][c*16+t], via LDS transpose ----
__global__ __launch_bounds__(256) void k_pack(const float* __restrict__ y,
                                              f16* __restrict__ Zh) {
  __shared__ f16 Lt[32][136];               // 128 k-vals per row, +8 pad
  const int tid = threadIdx.x;
  const int k0 = blockIdx.x * 128;
  const int i = tid >> 3, kq = tid & 7;     // 32 rows x 8 chunks of 16 floats
  const float4* src = reinterpret_cast<const float4*>(y + (size_t)i * NSTEP + k0 + kq * 16);
  const float4 v0 = src[0], v1 = src[1], v2 = src[2], v3 = src[3];
  f16x8 h0 = {(f16)v0.x, (f16)v0.y, (f16)v0.z, (f16)v0.w,
              (f16)v1.x, (f16)v1.y, (f16)v1.z, (f16)v1.w};
  f16x8 h1 = {(f16)v2.x, (f16)v2.y, (f16)v2.z, (f16)v2.w,
              (f16)v3.x, (f16)v3.y, (f16)v3.z, (f16)v3.w};
  f16x8* dst = reinterpret_cast<f16x8*>(&Lt[i][kq * 16]);
  dst[0] = h0; dst[1] = h1;
  __syncthreads();
  for (int r = tid; r < 512; r += 256) {    // 8 chunks x 16 t x 4 i-octets
    const int cl = r >> 6, t = (r >> 2) & 15, i0 = (r & 3) << 3;
    f16x8 hv;
#pragma unroll
    for (int d = 0; d < 8; ++d) hv[d] = Lt[i0 + d][cl * 16 + t];
    *reinterpret_cast<f16x8*>(Zh + (size_t)(blockIdx.x * 8 + cl) * KDIM + 64 + t * 32 + i0) = hv;
  }
}

// ------------- P1: M = A - L H, then squaring chain in LDS (fp32) -------------
__global__ __launch_bounds__(1024) void k_p1(const float* __restrict__ A,
                                             const float* __restrict__ H,
                                             const float* __restrict__ L,
                                             float* __restrict__ MP) {
  __shared__ float sm[2][64 * 68];
  const int tid = threadIdx.x;
  const int i = tid >> 4;
  const int j0 = (tid & 15) << 2;
  float a0 = A[i * 64 + j0 + 0], a1 = A[i * 64 + j0 + 1];
  float a2 = A[i * 64 + j0 + 2], a3 = A[i * 64 + j0 + 3];
  for (int q = 0; q < 32; ++q) {
    const float l = L[i * 32 + q];
    a0 -= l * H[q * 64 + j0 + 0];
    a1 -= l * H[q * 64 + j0 + 1];
    a2 -= l * H[q * 64 + j0 + 2];
    a3 -= l * H[q * 64 + j0 + 3];
  }
  sm[0][i * 68 + j0 + 0] = a0; sm[0][i * 68 + j0 + 1] = a1;
  sm[0][i * 68 + j0 + 2] = a2; sm[0][i * 68 + j0 + 3] = a3;
  MP[i * 64 + j0 + 0] = a0; MP[i * 64 + j0 + 1] = a1;
  MP[i * 64 + j0 + 2] = a2; MP[i * 64 + j0 + 3] = a3;
  __syncthreads();
  int cur = 0;
  for (int s = 1; s <= 11; ++s) {   // powers 2,4,8,16,...,2048
    float c0 = 0.f, c1 = 0.f, c2 = 0.f, c3 = 0.f;
    for (int k = 0; k < 64; ++k) {
      const float r = sm[cur][i * 68 + k];
      const float* col = &sm[cur][k * 68 + j0];
      c0 += r * col[0]; c1 += r * col[1]; c2 += r * col[2]; c3 += r * col[3];
    }
    sm[cur ^ 1][i * 68 + j0 + 0] = c0; sm[cur ^ 1][i * 68 + j0 + 1] = c1;
    sm[cur ^ 1][i * 68 + j0 + 2] = c2; sm[cur ^ 1][i * 68 + j0 + 3] = c3;
    const int slot = (s <= 4) ? s : (s == 11 ? 5 : -1);
    if (slot >= 0) {
      MP[slot * 4096 + i * 64 + j0 + 0] = c0;
      MP[slot * 4096 + i * 64 + j0 + 1] = c1;
      MP[slot * 4096 + i * 64 + j0 + 2] = c2;
      MP[slot * 4096 + i * 64 + j0 + 3] = c3;
    }
    cur ^= 1;
    __syncthreads();
  }
}

// ------ P2: block 0 = F chain + BOh(f16); block 1 = G chain + GCh(f16).
//        M-power operand held in REGISTERS (statically indexed, full unroll). ------
__global__ __launch_bounds__(1024) void k_p2(const float* __restrict__ H,
                                             const float* __restrict__ L,
                                             const float* __restrict__ MP,
                                             float* __restrict__ ws) {
  __shared__ float S[16 * 2048];   // F_t or G_t chain, t = 0..15
  f16* BOh = reinterpret_cast<f16*>(ws + OFF_BOH);
  f16* GCh = reinterpret_cast<f16*>(ws + OFF_GCH);
  const int tid = threadIdx.x;

  if (blockIdx.x == 0) {
    // ---- F chain: F_0 = H; F_{t+nf} = F_t * M^{nf}. thread owns col j. ----
    const int j = tid & 63, ibase = tid >> 6;    // ibase 0..15
    for (int e = tid; e < 2048; e += 1024) S[e] = H[e];
    __syncthreads();
    float Mcol[64];
    for (int r = 0; r < 4; ++r) {
      const int nf = 1 << r;
      const float* __restrict__ Mp = MP + r * 4096;
#pragma unroll
      for (int q = 0; q < 64; ++q) Mcol[q] = Mp[q * 64 + j];   // coalesced
      for (int t = 0; t < nf; ++t)
        for (int ig = 0; ig < 2; ++ig) {
          const int i = ibase + 16 * ig;
          const float* Frow = &S[t * 2048 + i * 64];           // wave-broadcast
          float acc = 0.f;
#pragma unroll
          for (int q = 0; q < 64; ++q) acc = fmaf(Frow[q], Mcol[q], acc);
          S[(nf + t) * 2048 + i * 64 + j] = acc;
        }
      __syncthreads();
    }
    // ---- BOh F-part + zero K-region (s>=t) ----
    for (int e = tid; e < MOUT * KDIM; e += 1024) {
      const int rr = e / KDIM, f = e - rr * KDIM;
      const int i = rr >> 4, t = rr & 15;
      if (f < 64) BOh[e] = (f16)S[t * 2048 + i * 64 + f];
      else { const int s = (f - 64) >> 5; if (s >= t) BOh[e] = (f16)0.f; }
    }
    // ---- K_d = F_d * L, scattered to BOh rows (k-region s<t, disjoint) ----
    const int ki = (tid >> 5) & 31, kq = tid & 31;
    for (int d = 0; d < 15; ++d) {
      const float* Frow = &S[d * 2048 + ki * 64];
      float kv = 0.f;
#pragma unroll
      for (int jj = 0; jj < 64; ++jj) kv = fmaf(Frow[jj], L[jj * 32 + kq], kv);
      const f16 kh = (f16)kv;
      for (int t = d + 1; t < 16; ++t)
        BOh[(size_t)(ki * 16 + t) * KDIM + 64 + (t - 1 - d) * 32 + kq] = kh;
    }
  } else {
    // ---- G chain: G_0 = L; G_{t+nf} = M^{nf} * G_t. thread owns row i. ----
    const int i = tid >> 4, qb = tid & 15;       // i 0..63
    for (int e = tid; e < 2048; e += 1024) S[e] = L[e];
    __syncthreads();
    float Mrow[64];
    for (int r = 0; r < 4; ++r) {
      const int nf = 1 << r;
      const float* __restrict__ Mp = MP + r * 4096;
#pragma unroll
      for (int p = 0; p < 64; ++p) Mrow[p] = Mp[i * 64 + p];
      for (int t = 0; t < nf; ++t)
        for (int qh = 0; qh < 2; ++qh) {
          const int q = qb + 16 * qh;
          float acc = 0.f;
#pragma unroll
          for (int p = 0; p < 64; ++p) acc = fmaf(Mrow[p], S[t * 2048 + p * 32 + q], acc);
          S[(nf + t) * 2048 + i * 32 + q] = acc;
        }
      __syncthreads();
    }
    // ---- GCh[j][t*32+ii] = (f16) G_{15-t}[j][ii] ----
    for (int e = tid; e < 64 * 512; e += 1024) {
      const int jj = e >> 9, f = e & 511, t = f >> 5, ii = f & 31;
      GCh[e] = (f16)S[(15 - t) * 2048 + jj * 32 + ii];
    }
  }
}

// ---- f16 MFMA GEMM, no LDS: C[nn][mm] = sum_k Ap[nn][k] * Bp[mm][k].
//      MODE 0: VT output [c][64], K=512, A k-offset 64 (GCh as B)
//      MODE 1: out[i*NSTEP + c*16 + t] with mm = i*16+t, K=576 (BOh as B) ----
template <int MODE>
__global__ __launch_bounds__(256) void k_mfma(const f16* __restrict__ Ap,
                                              const f16* __restrict__ Bp,
                                              float* __restrict__ outp) {
  constexpr int KSTEPS = MODE ? 18 : 16;
  constexpr int LDB = MODE ? KDIM : 512;
  constexpr int AOFF = MODE ? 0 : 64;
  const int tid = threadIdx.x;
  const int wave = tid >> 6, lane = tid & 63;
  const int l15 = lane & 15, lg = lane >> 4;
  const int nn0 = blockIdx.x * 128;
  const int mm0 = MODE ? blockIdx.y * 64 : 0;
  const f16* a0p = Ap + (size_t)(nn0 + wave * 32 + l15) * KDIM + AOFF + lg * 8;
  const f16* a1p = a0p + 16 * KDIM;
  const f16* bp = Bp + (size_t)(mm0 + l15) * LDB + lg * 8;
  f32x4 acc[2][4] = {};
#pragma unroll 2
  for (int ks = 0; ks < KSTEPS; ++ks) {
    const f16x8 a0 = *reinterpret_cast<const f16x8*>(a0p + ks * 32);
    const f16x8 a1 = *reinterpret_cast<const f16x8*>(a1p + ks * 32);
#pragma unroll
    for (int bf = 0; bf < 4; ++bf) {
      const f16x8 b = *reinterpret_cast<const f16x8*>(bp + (size_t)bf * 16 * LDB + ks * 32);
      acc[0][bf] = __builtin_amdgcn_mfma_f32_16x16x32_f16(a0, b, acc[0][bf], 0, 0, 0);
      acc[1][bf] = __builtin_amdgcn_mfma_f32_16x16x32_f16(a1, b, acc[1][bf], 0, 0, 0);
    }
  }
  // D layout: col = lane&15 (mm), row = lg*4 + reg (nn)  [m89-verified]
#pragma unroll
  for (int af = 0; af < 2; ++af)
#pragma unroll
    for (int bf = 0; bf < 4; ++bf)
#pragma unroll
      for (int rg = 0; rg < 4; ++rg) {
        const int c = nn0 + wave * 32 + af * 16 + lg * 4 + rg;
        const int mm = mm0 + bf * 16 + l15;
        if (MODE) {
          outp[(size_t)(mm >> 4) * NSTEP + (size_t)c * 16 + (mm & 15)] = acc[af][bf][rg];
        } else {
          outp[(size_t)c * 64 + mm] = acc[af][bf][rg];
        }
      }
}

// ---------------- scan matvec: row-in-registers + readlane broadcast ----------------
__device__ __forceinline__ float lane_bcast(float v, int l) {
  return __uint_as_float(__builtin_amdgcn_readlane(__float_as_uint(v), l));
}

__device__ __forceinline__ float matvec_step(const float* __restrict__ Prow, float x,
                                             float v) {
  float accA = v, accB = 0.f;
#pragma unroll
  for (int j = 0; j < 32; ++j) {
    accA = fmaf(Prow[j], lane_bcast(x, j), accA);
    accB = fmaf(Prow[j + 32], lane_bcast(x, j + 32), accB);
  }
  return accA + accB;
}

__global__ __launch_bounds__(64) void k_scanA(const float* __restrict__ MP,
                                              const float* __restrict__ VT,
                                              float* __restrict__ W) {
  const int lane = threadIdx.x;
  const int b = blockIdx.x;
  const float* P = MP + 4 * 4096;   // M^16
  float Prow[64];
#pragma unroll
  for (int j = 0; j < 64; ++j) Prow[j] = P[lane * 64 + j];
  const float* vbase = VT + (size_t)b * SB * 64;
  float x = 0.f;
  float v0 = vbase[lane];
  float v1 = vbase[64 + lane];
  for (int s = 0; s < SB; ++s) {
    x = matvec_step(Prow, x, v0);
    v0 = v1;
    v1 = (s + 2 < SB) ? vbase[(size_t)(s + 2) * 64 + lane] : 0.f;
  }
  W[b * 64 + lane] = x;
}

__global__ __launch_bounds__(64) void k_scanB(const float* __restrict__ MP,
                                              const float* __restrict__ W,
                                              float* __restrict__ XB) {
  const int lane = threadIdx.x;
  const float* Q = MP + 5 * 4096;   // M^2048
  float Qrow[64];
#pragma unroll
  for (int j = 0; j < 64; ++j) Qrow[j] = Q[lane * 64 + j];
  float x = 0.f;
  float v0 = W[lane];
  float v1 = W[64 + lane];
  for (int b = 0; b < NBLK; ++b) {
    XB[b * 64 + lane] = x;          // state at start of scan-block b
    x = matvec_step(Qrow, x, v0);
    v0 = v1;
    v1 = (b + 2 < NBLK) ? W[(b + 2) * 64 + lane] : 0.f;
  }
}

__global__ __launch_bounds__(64) void k_scanC(const float* __restrict__ MP,
                                              const float* __restrict__ VT,
                                              const float* __restrict__ XB,
                                              f16* __restrict__ Zh) {
  __shared__ float xt2[SB][68];     // [s][j]
  const int lane = threadIdx.x;
  const int b = blockIdx.x;
  const float* P = MP + 4 * 4096;
  float Prow[64];
#pragma unroll
  for (int j = 0; j < 64; ++j) Prow[j] = P[lane * 64 + j];
  const float* vbase = VT + (size_t)b * SB * 64;
  float x = XB[b * 64 + lane];
  float v0 = vbase[lane];
  float v1 = vbase[64 + lane];
  for (int s = 0; s < SB; ++s) {
    xt2[s][lane] = x;               // x_c BEFORE consuming v_c
    x = matvec_step(Prow, x, v0);
    v0 = v1;
    v1 = (s + 2 < SB) ? vbase[(size_t)(s + 2) * 64 + lane] : 0.f;
  }
  __syncthreads();
  for (int s = lane; s < SB; s += 64) {     // 2 rows per thread
    f16x8* dst = reinterpret_cast<f16x8*>(Zh + (size_t)(b * SB + s) * KDIM);
#pragma unroll
    for (int w = 0; w < 8; ++w) {
      f16x8 hv;
#pragma unroll
      for (int d = 0; d < 8; ++d) hv[d] = (f16)xt2[s][w * 8 + d];
      dst[w] = hv;
    }
  }
}

extern "C" void kernel_launch(void* const* d_in, const int* in_sizes, int n_in,
                              void* d_out, int out_size, void* d_ws, size_t ws_size,
                              hipStream_t stream) {
  const float* y = (const float*)d_in[0];
  const float* A = (const float*)d_in[1];
  const float* H = (const float*)d_in[2];
  const float* L = (const float*)d_in[3];
  float* ws = (float*)d_ws;
  f16* Zh   = reinterpret_cast<f16*>(ws + OFF_ZH);
  float* VT = ws + OFF_VT;
  float* MP = ws + OFF_MP;
  f16* BOh  = reinterpret_cast<f16*>(ws + OFF_BOH);
  f16* GCh  = reinterpret_cast<f16*>(ws + OFF_GCH);
  float* W  = ws + OFF_W;
  float* XB = ws + OFF_XB;
  float* out = (float*)d_out;

  k_pack<<<dim3(NSTEP / 128), dim3(256), 0, stream>>>(y, Zh);
  k_p1<<<dim3(1), dim3(1024), 0, stream>>>(A, H, L, MP);
  k_p2<<<dim3(2), dim3(1024), 0, stream>>>(H, L, MP, ws);
  // V GEMM (MFMA): VT[c][j] = sum_f Zh[c][64+f] * GCh[j][f]
  k_mfma<0><<<dim3(CCH / 128, 1), dim3(256), 0, stream>>>(Zh, GCh, VT);
  k_scanA<<<dim3(NBLK), dim3(64), 0, stream>>>(MP, VT, W);
  k_scanB<<<dim3(1), dim3(64), 0, stream>>>(MP, W, XB);
  k_scanC<<<dim3(NBLK), dim3(64), 0, stream>>>(MP, VT, XB, Zh);
  // Output GEMM (MFMA): out[i][c*16+t] = sum_k Zh[c][k] * BOh[i*16+t][k]
  k_mfma<1><<<dim3(CCH / 128, MOUT / 64), dim3(256), 0, stream>>>(Zh, BOh, out);
}

// Round 5
// 338.895 us; speedup vs baseline: 1.6737x; 1.6737x over previous
//
#include <hip/hip_runtime.h>
#include <hip/hip_bf16.h>

// Kalman recurrence, exact chunked parallelization. Round 5.
//   x[k+1] = M x[k] + L y[:,k],  M = A - L H,  yhat[:,k] = H x[k], x[0]=0
// Chunk T=16:  yhat[cT+t] = F_t x_c + sum_{s<t} K_{t-1-s} y[cT+s]
//   F_t = H M^t, K_d = H M^d L, v_c = sum_t M^{15-t} L y[cT+t]
//   x_{c+1} = P x_c + v_c, P = M^16.  3-level fp32 scan over C=16384 chunks.
// Round-5: (a) prep split into many-block short-chain kernels (k_p2 was 250-330us
// at 0.1% VALUBusy — 2-block latency-bound); (b) f16 operands stored in
// fragment-major tiles so every MFMA A/B load is a contiguous 1KiB per wave.

#define NSTEP 262144
#define T 16
#define CCH (NSTEP / T)          // 16384 chunks
#define KDIM (64 + 32 * T)       // 576
#define MOUT (32 * T)            // 512
#define NBLK 128                 // scan blocks
#define SB (CCH / NBLK)          // 128 chunks per scan block

typedef _Float16 f16;
typedef _Float16 f16x4 __attribute__((ext_vector_type(4)));
typedef _Float16 f16x8 __attribute__((ext_vector_type(8)));
typedef float f32x4 __attribute__((ext_vector_type(4)));

// Fragment-major tile layout for a [rows][K] f16 matrix:
//   slot(ct, ks, lg, l) = ((ct*KS + ks)*4 + lg)*16 + l   (one slot = 8 f16 = 16B)
//   element (r, k): ct=r>>4, l=r&15, ks=k>>5, lg=(k>>3)&3, e=k&7
// A wave's MFMA fragment load (lane = lg*16+l15) is then 64 consecutive 16B.

// ---- workspace layout (float units) ----
#define OFF_ZH 0                          // Zh tiled: CCH rows x 576 k (KS=18)
#define SZ_ZH  (CCH * KDIM / 2)
#define OFF_VT (OFF_ZH + SZ_ZH)           // VT: f32 [CCH][64]
#define SZ_VT  (CCH * 64)
#define OFF_MP (OFF_VT + SZ_VT)           // M powers: 0:M 1:M2 2:M4 3:M8 4:M16 5:M2048 6:M3 7:M12
#define SZ_MP  (8 * 4096)
#define OFF_BO (OFF_MP + SZ_MP)           // BOh tiled: 512 rows x 576 k (KS=18)
#define SZ_BO  (MOUT * KDIM / 2)
#define OFF_GC (OFF_BO + SZ_BO)           // GCh tiled: 64 rows x 512 k (KS=16)
#define SZ_GC  (64 * 512 / 2)
#define OFF_FB (OFF_GC + SZ_GC)           // Fbuf: f32 16 x (32x64)
#define SZ_FB  (16 * 2048)
#define OFF_GB (OFF_FB + SZ_FB)           // Gbuf: f32 16 x (64x32)
#define SZ_GB  (16 * 2048)
#define OFF_KD (OFF_GB + SZ_GB)           // Kd: f32 15 x (32x32)
#define SZ_KD  (15 * 1024)
#define OFF_W  (OFF_KD + SZ_KD)           // [128][64]
#define OFF_XB (OFF_W + NBLK * 64)        // [128][64]

// ---- pack: Zh[c][64+t*32+i] = (f16) y[i][c*16+t], tiled layout, 16 chunks/block ----
__global__ __launch_bounds__(256) void k_pack(const float* __restrict__ y,
                                              f16* __restrict__ Zt) {
  __shared__ f16 Lt[32][264];               // [i][local timestep 0..255], +8 pad
  const int tid = threadIdx.x;
  const int ct = blockIdx.x;                // c-tile: chunks ct*16 .. ct*16+15
  const size_t colbase = (size_t)ct * 256;  // timestep base
#pragma unroll
  for (int v = 0; v < 8; ++v) {
    const int fidx = v * 256 + tid;         // 2048 float4 over [32][256]
    const int row = fidx >> 6, col4 = fidx & 63;
    const float4 w = *reinterpret_cast<const float4*>(y + (size_t)row * NSTEP + colbase + col4 * 4);
    f16x4 h = {(f16)w.x, (f16)w.y, (f16)w.z, (f16)w.w};
    *reinterpret_cast<f16x4*>(&Lt[row][col4 * 4]) = h;
  }
  __syncthreads();
#pragma unroll
  for (int v = 0; v < 4; ++v) {
    const int s = v * 256 + tid;            // slot within block: ((t*4)+lg)*16 + l
    const int l = s & 15, lg = (s >> 4) & 3, t = s >> 6;
    f16x8 hv;
#pragma unroll
    for (int e = 0; e < 8; ++e) hv[e] = Lt[lg * 8 + e][l * 16 + t];
    *reinterpret_cast<f16x8*>(Zt + ((size_t)(ct * 18 + 2 + t) * 64 + lg * 16 + l) * 8) = hv;
  }
}

// ---- P1: M = A - L H; powers M2,M3,M4,M8,M12,M16,M2048 via LDS matmuls;
//      also seeds Fbuf[0]=H, Gbuf[0]=L ----
__global__ __launch_bounds__(1024) void k_p1(const float* __restrict__ A,
                                             const float* __restrict__ H,
                                             const float* __restrict__ L,
                                             float* __restrict__ MP,
                                             float* __restrict__ Fb,
                                             float* __restrict__ Gb) {
  __shared__ float B0[64 * 68], B1[64 * 68], B2[64 * 68];
  const int tid = threadIdx.x;
  const int i = tid >> 4;
  const int j0 = (tid & 15) << 2;

  // mm: D[i][j0..3] = sum_k X[i][k]*Y[k][j0..3]; optional LDS dst + global dst
  auto mm = [&](float* ldst, const float* X, const float* Y, float* gdst) {
    float c0 = 0.f, c1 = 0.f, c2 = 0.f, c3 = 0.f;
    for (int k = 0; k < 64; ++k) {
      const float r = X[i * 68 + k];
      const float* col = &Y[k * 68 + j0];
      c0 = fmaf(r, col[0], c0); c1 = fmaf(r, col[1], c1);
      c2 = fmaf(r, col[2], c2); c3 = fmaf(r, col[3], c3);
    }
    if (ldst) { ldst[i * 68 + j0 + 0] = c0; ldst[i * 68 + j0 + 1] = c1;
                ldst[i * 68 + j0 + 2] = c2; ldst[i * 68 + j0 + 3] = c3; }
    if (gdst) { gdst[i * 64 + j0 + 0] = c0; gdst[i * 64 + j0 + 1] = c1;
                gdst[i * 64 + j0 + 2] = c2; gdst[i * 64 + j0 + 3] = c3; }
  };

  // M = A - L H
  float a0 = A[i * 64 + j0 + 0], a1 = A[i * 64 + j0 + 1];
  float a2 = A[i * 64 + j0 + 2], a3 = A[i * 64 + j0 + 3];
  for (int q = 0; q < 32; ++q) {
    const float l = L[i * 32 + q];
    a0 -= l * H[q * 64 + j0 + 0]; a1 -= l * H[q * 64 + j0 + 1];
    a2 -= l * H[q * 64 + j0 + 2]; a3 -= l * H[q * 64 + j0 + 3];
  }
  B0[i * 68 + j0 + 0] = a0; B0[i * 68 + j0 + 1] = a1;
  B0[i * 68 + j0 + 2] = a2; B0[i * 68 + j0 + 3] = a3;
  MP[i * 64 + j0 + 0] = a0; MP[i * 64 + j0 + 1] = a1;
  MP[i * 64 + j0 + 2] = a2; MP[i * 64 + j0 + 3] = a3;
  for (int e = tid; e < 2048; e += 1024) { Fb[e] = H[e]; Gb[e] = L[e]; }
  __syncthreads();

  mm(B1, B0, B0, MP + 1 * 4096); __syncthreads();   // M2
  mm(nullptr, B1, B0, MP + 6 * 4096); __syncthreads(); // M3 = M2*M
  mm(B2, B1, B1, MP + 2 * 4096); __syncthreads();   // M4
  mm(B0, B2, B2, MP + 3 * 4096); __syncthreads();   // M8 (overwrites M)
  mm(nullptr, B2, B0, MP + 7 * 4096); __syncthreads(); // M12 = M4*M8
  mm(B1, B0, B0, MP + 4 * 4096); __syncthreads();   // M16
  float* cur = B1; float* oth = B2;
  for (int s2 = 0; s2 < 7; ++s2) {                  // M32..M2048
    mm(oth, cur, cur, (s2 == 6) ? MP + 5 * 4096 : nullptr);
    __syncthreads();
    float* tmp = cur; cur = oth; oth = tmp;
  }
}

// ---- FG: F_{dst} = F_{src} * M^p  /  G_{dst} = M^p * G_{src}; 1 matmul/block ----
__global__ __launch_bounds__(256) void k_fg(const float* __restrict__ MP,
                                            float* __restrict__ Fb,
                                            float* __restrict__ Gb,
                                            const int phase) {
  const int tid = threadIdx.x;
  const int nHalf = phase ? 12 : 3;
  const int half = blockIdx.x / nHalf, r = blockIdx.x % nHalf;
  int src, dst, msl;
  if (phase == 0) { src = 0; dst = r + 1; msl = (r == 0) ? 0 : (r == 1) ? 1 : 6; }
  else { const int b = r / 4 + 1, s = r % 4; src = s; dst = 4 * b + s;
         msl = (b == 1) ? 2 : (b == 2) ? 3 : 7; }
  const float* __restrict__ Mx = MP + msl * 4096;
  if (half == 0) {
    const int j = tid & 63, ih = tid >> 6;
    const float* Fs = Fb + src * 2048;
    float* Fd = Fb + dst * 2048;
#pragma unroll
    for (int u = 0; u < 8; ++u) {
      const int i = ih * 8 + u;
      float acc = 0.f;
#pragma unroll 8
      for (int q = 0; q < 64; ++q) acc = fmaf(Fs[i * 64 + q], Mx[q * 64 + j], acc);
      Fd[i * 64 + j] = acc;
    }
  } else {
    const int q = tid & 31, ih = tid >> 5;
    const float* Gs = Gb + src * 2048;
    float* Gd = Gb + dst * 2048;
#pragma unroll
    for (int u = 0; u < 8; ++u) {
      const int i = ih * 8 + u;
      float acc = 0.f;
#pragma unroll 8
      for (int p = 0; p < 64; ++p) acc = fmaf(Mx[i * 64 + p], Gs[p * 32 + q], acc);
      Gd[i * 32 + q] = acc;
    }
  }
}

// ---- KD: K_d = F_d * L (15 x 32x32) ----
__global__ __launch_bounds__(256) void k_kd(const float* __restrict__ Fb,
                                            const float* __restrict__ L,
                                            float* __restrict__ Kd) {
  const int o = blockIdx.x * 256 + threadIdx.x;   // < 15360
  const int d = o >> 10, i = (o >> 5) & 31, q = o & 31;
  float acc = 0.f;
#pragma unroll 8
  for (int j = 0; j < 64; ++j) acc = fmaf(Fb[d * 2048 + i * 64 + j], L[j * 32 + q], acc);
  Kd[o] = acc;
}

// ---- ASM: assemble BOh (tiled f16) and GCh (tiled f16) ----
__global__ __launch_bounds__(256) void k_asm(const float* __restrict__ Fb,
                                             const float* __restrict__ Gb,
                                             const float* __restrict__ Kd,
                                             f16* __restrict__ BOt,
                                             f16* __restrict__ GCt) {
  const int sid = blockIdx.x * 256 + threadIdx.x;
  if (sid < 512 * 72) {            // BOh: 32 mt x 18 ks x 4 lg x 16 l slots
    const int l = sid & 15, lg = (sid >> 4) & 3;
    const int t18 = sid >> 6;
    const int mt = t18 / 18, ks = t18 - mt * 18;
    const int i = mt, t = l;
    const int k0 = ks * 32 + lg * 8;
    f16x8 hv;
    if (k0 + 7 < 64) {
#pragma unroll
      for (int e = 0; e < 8; ++e) hv[e] = (f16)Fb[t * 2048 + i * 64 + k0 + e];
    } else {
      const int kk = k0 - 64;
      const int s = kk >> 5, q0 = kk & 31;
      if (s < t) {
        const int d = t - 1 - s;
#pragma unroll
        for (int e = 0; e < 8; ++e) hv[e] = (f16)Kd[d * 1024 + i * 32 + q0 + e];
      } else {
#pragma unroll
        for (int e = 0; e < 8; ++e) hv[e] = (f16)0.f;
      }
    }
    *reinterpret_cast<f16x8*>(BOt + (size_t)sid * 8) = hv;
  } else {                          // GCh: 4 jt x 16 ks x 4 lg x 16 l slots
    const int sid2 = sid - 512 * 72;
    if (sid2 < 4096) {
      const int l = sid2 & 15, lg = (sid2 >> 4) & 3;
      const int t16 = sid2 >> 6;
      const int jt = t16 >> 4, ks = t16 & 15;
      const int j = jt * 16 + l;
      const int ii = lg * 8;
      f16x8 hv;
#pragma unroll
      for (int e = 0; e < 8; ++e) hv[e] = (f16)Gb[(15 - ks) * 2048 + j * 32 + ii + e];
      *reinterpret_cast<f16x8*>(GCt + (size_t)sid2 * 8) = hv;
    }
  }
}

// ---- f16 MFMA GEMM on tiled operands. C[c][mm] = sum_k Zh[c][k]*B[mm][k].
//      MODE 0: B=GCh (KS_B=16, A ks 2..17), out VT[c][64]
//      MODE 1: B=BOh (KS_B=18, A ks 0..17), out d_out[i*NSTEP + c*16 + t] ----
template <int MODE>
__global__ __launch_bounds__(256) void k_mfma(const f16* __restrict__ At,
                                              const f16* __restrict__ Bt,
                                              float* __restrict__ outp) {
  constexpr int KSTEPS = MODE ? 18 : 16;
  constexpr int AKS0 = MODE ? 0 : 2;
  constexpr int KSB = MODE ? 18 : 16;
  const int tid = threadIdx.x;
  const int wave = tid >> 6, lane = tid & 63;
  const int l15 = lane & 15, lg = lane >> 4;
  const int nn0 = blockIdx.x * 128;
  const int ct0 = blockIdx.x * 8 + wave * 2;
  const int bt0 = MODE ? blockIdx.y * 4 : 0;
  const int laneoff = (lg * 16 + l15) * 8;
  f32x4 acc[2][4] = {};
#pragma unroll 2
  for (int su = 0; su < KSTEPS; ++su) {
    const f16x8 a0 = *reinterpret_cast<const f16x8*>(At + (size_t)((ct0 + 0) * 18 + AKS0 + su) * 512 + laneoff);
    const f16x8 a1 = *reinterpret_cast<const f16x8*>(At + (size_t)((ct0 + 1) * 18 + AKS0 + su) * 512 + laneoff);
#pragma unroll
    for (int bf = 0; bf < 4; ++bf) {
      const f16x8 b = *reinterpret_cast<const f16x8*>(Bt + (size_t)((bt0 + bf) * KSB + su) * 512 + laneoff);
      acc[0][bf] = __builtin_amdgcn_mfma_f32_16x16x32_f16(a0, b, acc[0][bf], 0, 0, 0);
      acc[1][bf] = __builtin_amdgcn_mfma_f32_16x16x32_f16(a1, b, acc[1][bf], 0, 0, 0);
    }
  }
  // D layout: col = lane&15 (mm), row = lg*4 + reg (c)  [m89-verified]
#pragma unroll
  for (int af = 0; af < 2; ++af)
#pragma unroll
    for (int bf = 0; bf < 4; ++bf)
#pragma unroll
      for (int rg = 0; rg < 4; ++rg) {
        const int c = nn0 + wave * 32 + af * 16 + lg * 4 + rg;
        const int mm = bt0 * 16 + bf * 16 + l15;
        if (MODE) {
          outp[(size_t)(mm >> 4) * NSTEP + (size_t)c * 16 + (mm & 15)] = acc[af][bf][rg];
        } else {
          outp[(size_t)c * 64 + mm] = acc[af][bf][rg];
        }
      }
}

// ---------------- scan matvec: row-in-registers + readlane broadcast ----------------
__device__ __forceinline__ float lane_bcast(float v, int l) {
  return __uint_as_float(__builtin_amdgcn_readlane(__float_as_uint(v), l));
}

__device__ __forceinline__ float matvec_step(const float* __restrict__ Prow, float x,
                                             float v) {
  float accA = v, accB = 0.f;
#pragma unroll
  for (int j = 0; j < 32; ++j) {
    accA = fmaf(Prow[j], lane_bcast(x, j), accA);
    accB = fmaf(Prow[j + 32], lane_bcast(x, j + 32), accB);
  }
  return accA + accB;
}

__global__ __launch_bounds__(64) void k_scanA(const float* __restrict__ MP,
                                              const float* __restrict__ VT,
                                              float* __restrict__ W) {
  const int lane = threadIdx.x;
  const int b = blockIdx.x;
  const float* P = MP + 4 * 4096;   // M^16
  float Prow[64];
#pragma unroll
  for (int j = 0; j < 64; ++j) Prow[j] = P[lane * 64 + j];
  const float* vbase = VT + (size_t)b * SB * 64;
  float x = 0.f;
  float v0 = vbase[lane];
  float v1 = vbase[64 + lane];
  for (int s = 0; s < SB; ++s) {
    x = matvec_step(Prow, x, v0);
    v0 = v1;
    v1 = (s + 2 < SB) ? vbase[(size_t)(s + 2) * 64 + lane] : 0.f;
  }
  W[b * 64 + lane] = x;
}

__global__ __launch_bounds__(64) void k_scanB(const float* __restrict__ MP,
                                              const float* __restrict__ W,
                                              float* __restrict__ XB) {
  const int lane = threadIdx.x;
  const float* Q = MP + 5 * 4096;   // M^2048
  float Qrow[64];
#pragma unroll
  for (int j = 0; j < 64; ++j) Qrow[j] = Q[lane * 64 + j];
  float x = 0.f;
  float v0 = W[lane];
  float v1 = W[64 + lane];
  for (int b = 0; b < NBLK; ++b) {
    XB[b * 64 + lane] = x;          // state at start of scan-block b
    x = matvec_step(Qrow, x, v0);
    v0 = v1;
    v1 = (b + 2 < NBLK) ? W[(b + 2) * 64 + lane] : 0.f;
  }
}

__global__ __launch_bounds__(64) void k_scanC(const float* __restrict__ MP,
                                              const float* __restrict__ VT,
                                              const float* __restrict__ XB,
                                              f16* __restrict__ Zt) {
  __shared__ float xt2[SB][68];     // [s][j]
  const int lane = threadIdx.x;
  const int b = blockIdx.x;
  const float* P = MP + 4 * 4096;
  float Prow[64];
#pragma unroll
  for (int j = 0; j < 64; ++j) Prow[j] = P[lane * 64 + j];
  const float* vbase = VT + (size_t)b * SB * 64;
  float x = XB[b * 64 + lane];
  float v0 = vbase[lane];
  float v1 = vbase[64 + lane];
  for (int s = 0; s < SB; ++s) {
    xt2[s][lane] = x;               // x_c BEFORE consuming v_c
    x = matvec_step(Prow, x, v0);
    v0 = v1;
    v1 = (s + 2 < SB) ? vbase[(size_t)(s + 2) * 64 + lane] : 0.f;
  }
  __syncthreads();
  // write x-part (k=0..63 → ks 0..1) of tiled Zh
#pragma unroll
  for (int h = 0; h < 2; ++h) {
    const int s = h * 64 + lane;
    const int c = b * SB + s;
    const int ct = c >> 4, l = c & 15;
#pragma unroll
    for (int ks = 0; ks < 2; ++ks)
#pragma unroll
      for (int lg = 0; lg < 4; ++lg) {
        f16x8 hv;
#pragma unroll
        for (int e = 0; e < 8; ++e) hv[e] = (f16)xt2[s][ks * 32 + lg * 8 + e];
        *reinterpret_cast<f16x8*>(Zt + ((size_t)(ct * 18 + ks) * 64 + lg * 16 + l) * 8) = hv;
      }
  }
}

extern "C" void kernel_launch(void* const* d_in, const int* in_sizes, int n_in,
                              void* d_out, int out_size, void* d_ws, size_t ws_size,
                              hipStream_t stream) {
  const float* y = (const float*)d_in[0];
  const float* A = (const float*)d_in[1];
  const float* H = (const float*)d_in[2];
  const float* L = (const float*)d_in[3];
  float* ws = (float*)d_ws;
  f16* Zt   = reinterpret_cast<f16*>(ws + OFF_ZH);
  float* VT = ws + OFF_VT;
  float* MP = ws + OFF_MP;
  f16* BOt  = reinterpret_cast<f16*>(ws + OFF_BO);
  f16* GCt  = reinterpret_cast<f16*>(ws + OFF_GC);
  float* Fb = ws + OFF_FB;
  float* Gb = ws + OFF_GB;
  float* Kd = ws + OFF_KD;
  float* W  = ws + OFF_W;
  float* XB = ws + OFF_XB;
  float* out = (float*)d_out;

  k_pack<<<dim3(CCH / 16), dim3(256), 0, stream>>>(y, Zt);
  k_p1<<<dim3(1), dim3(1024), 0, stream>>>(A, H, L, MP, Fb, Gb);
  k_fg<<<dim3(6), dim3(256), 0, stream>>>(MP, Fb, Gb, 0);
  k_fg<<<dim3(24), dim3(256), 0, stream>>>(MP, Fb, Gb, 1);
  k_kd<<<dim3(60), dim3(256), 0, stream>>>(Fb, L, Kd);
  k_asm<<<dim3(160), dim3(256), 0, stream>>>(Fb, Gb, Kd, BOt, GCt);
  // V GEMM (MFMA): VT[c][j] = sum_f Zh[c][64+f] * GCh[j][f]
  k_mfma<0><<<dim3(CCH / 128, 1), dim3(256), 0, stream>>>(Zt, GCt, VT);
  k_scanA<<<dim3(NBLK), dim3(64), 0, stream>>>(MP, VT, W);
  k_scanB<<<dim3(1), dim3(64), 0, stream>>>(MP, W, XB);
  k_scanC<<<dim3(NBLK), dim3(64), 0, stream>>>(MP, VT, XB, Zt);
  // Output GEMM (MFMA): out[i][c*16+t] = sum_k Zh[c][k] * BOh[i*16+t][k]
  k_mfma<1><<<dim3(CCH / 128, MOUT / 64), dim3(256), 0, stream>>>(Zt, BOt, out);
}

// Round 6
// 334.154 us; speedup vs baseline: 1.6975x; 1.0142x over previous
//
#include <hip/hip_runtime.h>
#include <hip/hip_bf16.h>

// Kalman recurrence, exact chunked parallelization. Round 6.
//   x[k+1] = M x[k] + L y[:,k],  M = A - L H,  yhat[:,k] = H x[k], x[0]=0
// Chunk T=16:  yhat[cT+t] = F_t x_c + sum_{s<t} K_{t-1-s} y[cT+s]
//   F_t = H M^t, K_d = H M^d L, v_c = sum_t M^{15-t} L y[cT+t]
//   x_{c+1} = P x_c + v_c, P = M^16.  3-level fp32 scan over C=16384 chunks.
// Round-6: scan kernels get __launch_bounds__(64,1) (VGPR_Count was 40 -> Prow[64]
// was NOT register-resident; compiler re-read P from L2 inside the serial loop,
// 55us at 5% VALUBusy) + 4-chain dot product to halve the FMA latency chain.

#define NSTEP 262144
#define T 16
#define CCH (NSTEP / T)          // 16384 chunks
#define KDIM (64 + 32 * T)       // 576
#define MOUT (32 * T)            // 512
#define NBLK 128                 // scan blocks
#define SB (CCH / NBLK)          // 128 chunks per scan block

typedef _Float16 f16;
typedef _Float16 f16x4 __attribute__((ext_vector_type(4)));
typedef _Float16 f16x8 __attribute__((ext_vector_type(8)));
typedef float f32x4 __attribute__((ext_vector_type(4)));

// Fragment-major tile layout for a [rows][K] f16 matrix:
//   slot(ct, ks, lg, l) = ((ct*KS + ks)*4 + lg)*16 + l   (one slot = 8 f16 = 16B)
//   element (r, k): ct=r>>4, l=r&15, ks=k>>5, lg=(k>>3)&3, e=k&7
// A wave's MFMA fragment load (lane = lg*16+l15) is then 64 consecutive 16B.

// ---- workspace layout (float units) ----
#define OFF_ZH 0                          // Zh tiled: CCH rows x 576 k (KS=18)
#define SZ_ZH  (CCH * KDIM / 2)
#define OFF_VT (OFF_ZH + SZ_ZH)           // VT: f32 [CCH][64]
#define SZ_VT  (CCH * 64)
#define OFF_MP (OFF_VT + SZ_VT)           // M powers: 0:M 1:M2 2:M4 3:M8 4:M16 5:M2048 6:M3 7:M12
#define SZ_MP  (8 * 4096)
#define OFF_BO (OFF_MP + SZ_MP)           // BOh tiled: 512 rows x 576 k (KS=18)
#define SZ_BO  (MOUT * KDIM / 2)
#define OFF_GC (OFF_BO + SZ_BO)           // GCh tiled: 64 rows x 512 k (KS=16)
#define SZ_GC  (64 * 512 / 2)
#define OFF_FB (OFF_GC + SZ_GC)           // Fbuf: f32 16 x (32x64)
#define SZ_FB  (16 * 2048)
#define OFF_GB (OFF_FB + SZ_FB)           // Gbuf: f32 16 x (64x32)
#define SZ_GB  (16 * 2048)
#define OFF_KD (OFF_GB + SZ_GB)           // Kd: f32 15 x (32x32)
#define SZ_KD  (15 * 1024)
#define OFF_W  (OFF_KD + SZ_KD)           // [128][64]
#define OFF_XB (OFF_W + NBLK * 64)        // [128][64]

// ---- pack: Zh[c][64+t*32+i] = (f16) y[i][c*16+t], tiled layout, 16 chunks/block ----
__global__ __launch_bounds__(256) void k_pack(const float* __restrict__ y,
                                              f16* __restrict__ Zt) {
  __shared__ f16 Lt[32][264];               // [i][local timestep 0..255], +8 pad
  const int tid = threadIdx.x;
  const int ct = blockIdx.x;                // c-tile: chunks ct*16 .. ct*16+15
  const size_t colbase = (size_t)ct * 256;  // timestep base
#pragma unroll
  for (int v = 0; v < 8; ++v) {
    const int fidx = v * 256 + tid;         // 2048 float4 over [32][256]
    const int row = fidx >> 6, col4 = fidx & 63;
    const float4 w = *reinterpret_cast<const float4*>(y + (size_t)row * NSTEP + colbase + col4 * 4);
    f16x4 h = {(f16)w.x, (f16)w.y, (f16)w.z, (f16)w.w};
    *reinterpret_cast<f16x4*>(&Lt[row][col4 * 4]) = h;
  }
  __syncthreads();
#pragma unroll
  for (int v = 0; v < 4; ++v) {
    const int s = v * 256 + tid;            // slot within block: ((t*4)+lg)*16 + l
    const int l = s & 15, lg = (s >> 4) & 3, t = s >> 6;
    f16x8 hv;
#pragma unroll
    for (int e = 0; e < 8; ++e) hv[e] = Lt[lg * 8 + e][l * 16 + t];
    *reinterpret_cast<f16x8*>(Zt + ((size_t)(ct * 18 + 2 + t) * 64 + lg * 16 + l) * 8) = hv;
  }
}

// ---- P1: M = A - L H; powers M2,M3,M4,M8,M12,M16,M2048 via LDS matmuls;
//      also seeds Fbuf[0]=H, Gbuf[0]=L ----
__global__ __launch_bounds__(1024) void k_p1(const float* __restrict__ A,
                                             const float* __restrict__ H,
                                             const float* __restrict__ L,
                                             float* __restrict__ MP,
                                             float* __restrict__ Fb,
                                             float* __restrict__ Gb) {
  __shared__ float B0[64 * 68], B1[64 * 68], B2[64 * 68];
  const int tid = threadIdx.x;
  const int i = tid >> 4;
  const int j0 = (tid & 15) << 2;

  // mm: D[i][j0..3] = sum_k X[i][k]*Y[k][j0..3]; optional LDS dst + global dst
  auto mm = [&](float* ldst, const float* X, const float* Y, float* gdst) {
    float c0 = 0.f, c1 = 0.f, c2 = 0.f, c3 = 0.f;
    for (int k = 0; k < 64; ++k) {
      const float r = X[i * 68 + k];
      const float* col = &Y[k * 68 + j0];
      c0 = fmaf(r, col[0], c0); c1 = fmaf(r, col[1], c1);
      c2 = fmaf(r, col[2], c2); c3 = fmaf(r, col[3], c3);
    }
    if (ldst) { ldst[i * 68 + j0 + 0] = c0; ldst[i * 68 + j0 + 1] = c1;
                ldst[i * 68 + j0 + 2] = c2; ldst[i * 68 + j0 + 3] = c3; }
    if (gdst) { gdst[i * 64 + j0 + 0] = c0; gdst[i * 64 + j0 + 1] = c1;
                gdst[i * 64 + j0 + 2] = c2; gdst[i * 64 + j0 + 3] = c3; }
  };

  // M = A - L H
  float a0 = A[i * 64 + j0 + 0], a1 = A[i * 64 + j0 + 1];
  float a2 = A[i * 64 + j0 + 2], a3 = A[i * 64 + j0 + 3];
  for (int q = 0; q < 32; ++q) {
    const float l = L[i * 32 + q];
    a0 -= l * H[q * 64 + j0 + 0]; a1 -= l * H[q * 64 + j0 + 1];
    a2 -= l * H[q * 64 + j0 + 2]; a3 -= l * H[q * 64 + j0 + 3];
  }
  B0[i * 68 + j0 + 0] = a0; B0[i * 68 + j0 + 1] = a1;
  B0[i * 68 + j0 + 2] = a2; B0[i * 68 + j0 + 3] = a3;
  MP[i * 64 + j0 + 0] = a0; MP[i * 64 + j0 + 1] = a1;
  MP[i * 64 + j0 + 2] = a2; MP[i * 64 + j0 + 3] = a3;
  for (int e = tid; e < 2048; e += 1024) { Fb[e] = H[e]; Gb[e] = L[e]; }
  __syncthreads();

  mm(B1, B0, B0, MP + 1 * 4096); __syncthreads();   // M2
  mm(nullptr, B1, B0, MP + 6 * 4096); __syncthreads(); // M3 = M2*M
  mm(B2, B1, B1, MP + 2 * 4096); __syncthreads();   // M4
  mm(B0, B2, B2, MP + 3 * 4096); __syncthreads();   // M8 (overwrites M)
  mm(nullptr, B2, B0, MP + 7 * 4096); __syncthreads(); // M12 = M4*M8
  mm(B1, B0, B0, MP + 4 * 4096); __syncthreads();   // M16
  float* cur = B1; float* oth = B2;
  for (int s2 = 0; s2 < 7; ++s2) {                  // M32..M2048
    mm(oth, cur, cur, (s2 == 6) ? MP + 5 * 4096 : nullptr);
    __syncthreads();
    float* tmp = cur; cur = oth; oth = tmp;
  }
}

// ---- FG: F_{dst} = F_{src} * M^p  /  G_{dst} = M^p * G_{src}; 1 matmul/block ----
__global__ __launch_bounds__(256) void k_fg(const float* __restrict__ MP,
                                            float* __restrict__ Fb,
                                            float* __restrict__ Gb,
                                            const int phase) {
  const int tid = threadIdx.x;
  const int nHalf = phase ? 12 : 3;
  const int half = blockIdx.x / nHalf, r = blockIdx.x % nHalf;
  int src, dst, msl;
  if (phase == 0) { src = 0; dst = r + 1; msl = (r == 0) ? 0 : (r == 1) ? 1 : 6; }
  else { const int b = r / 4 + 1, s = r % 4; src = s; dst = 4 * b + s;
         msl = (b == 1) ? 2 : (b == 2) ? 3 : 7; }
  const float* __restrict__ Mx = MP + msl * 4096;
  if (half == 0) {
    const int j = tid & 63, ih = tid >> 6;
    const float* Fs = Fb + src * 2048;
    float* Fd = Fb + dst * 2048;
#pragma unroll
    for (int u = 0; u < 8; ++u) {
      const int i = ih * 8 + u;
      float acc = 0.f;
#pragma unroll 8
      for (int q = 0; q < 64; ++q) acc = fmaf(Fs[i * 64 + q], Mx[q * 64 + j], acc);
      Fd[i * 64 + j] = acc;
    }
  } else {
    const int q = tid & 31, ih = tid >> 5;
    const float* Gs = Gb + src * 2048;
    float* Gd = Gb + dst * 2048;
#pragma unroll
    for (int u = 0; u < 8; ++u) {
      const int i = ih * 8 + u;
      float acc = 0.f;
#pragma unroll 8
      for (int p = 0; p < 64; ++p) acc = fmaf(Mx[i * 64 + p], Gs[p * 32 + q], acc);
      Gd[i * 32 + q] = acc;
    }
  }
}

// ---- KD: K_d = F_d * L (15 x 32x32) ----
__global__ __launch_bounds__(256) void k_kd(const float* __restrict__ Fb,
                                            const float* __restrict__ L,
                                            float* __restrict__ Kd) {
  const int o = blockIdx.x * 256 + threadIdx.x;   // < 15360
  const int d = o >> 10, i = (o >> 5) & 31, q = o & 31;
  float acc = 0.f;
#pragma unroll 8
  for (int j = 0; j < 64; ++j) acc = fmaf(Fb[d * 2048 + i * 64 + j], L[j * 32 + q], acc);
  Kd[o] = acc;
}

// ---- ASM: assemble BOh (tiled f16) and GCh (tiled f16) ----
__global__ __launch_bounds__(256) void k_asm(const float* __restrict__ Fb,
                                             const float* __restrict__ Gb,
                                             const float* __restrict__ Kd,
                                             f16* __restrict__ BOt,
                                             f16* __restrict__ GCt) {
  const int sid = blockIdx.x * 256 + threadIdx.x;
  if (sid < 512 * 72) {            // BOh: 32 mt x 18 ks x 4 lg x 16 l slots
    const int l = sid & 15, lg = (sid >> 4) & 3;
    const int t18 = sid >> 6;
    const int mt = t18 / 18, ks = t18 - mt * 18;
    const int i = mt, t = l;
    const int k0 = ks * 32 + lg * 8;
    f16x8 hv;
    if (k0 + 7 < 64) {
#pragma unroll
      for (int e = 0; e < 8; ++e) hv[e] = (f16)Fb[t * 2048 + i * 64 + k0 + e];
    } else {
      const int kk = k0 - 64;
      const int s = kk >> 5, q0 = kk & 31;
      if (s < t) {
        const int d = t - 1 - s;
#pragma unroll
        for (int e = 0; e < 8; ++e) hv[e] = (f16)Kd[d * 1024 + i * 32 + q0 + e];
      } else {
#pragma unroll
        for (int e = 0; e < 8; ++e) hv[e] = (f16)0.f;
      }
    }
    *reinterpret_cast<f16x8*>(BOt + (size_t)sid * 8) = hv;
  } else {                          // GCh: 4 jt x 16 ks x 4 lg x 16 l slots
    const int sid2 = sid - 512 * 72;
    if (sid2 < 4096) {
      const int l = sid2 & 15, lg = (sid2 >> 4) & 3;
      const int t16 = sid2 >> 6;
      const int jt = t16 >> 4, ks = t16 & 15;
      const int j = jt * 16 + l;
      const int ii = lg * 8;
      f16x8 hv;
#pragma unroll
      for (int e = 0; e < 8; ++e) hv[e] = (f16)Gb[(15 - ks) * 2048 + j * 32 + ii + e];
      *reinterpret_cast<f16x8*>(GCt + (size_t)sid2 * 8) = hv;
    }
  }
}

// ---- f16 MFMA GEMM on tiled operands. C[c][mm] = sum_k Zh[c][k]*B[mm][k].
//      MODE 0: B=GCh (KS_B=16, A ks 2..17), out VT[c][64]
//      MODE 1: B=BOh (KS_B=18, A ks 0..17), out d_out[i*NSTEP + c*16 + t] ----
template <int MODE>
__global__ __launch_bounds__(256) void k_mfma(const f16* __restrict__ At,
                                              const f16* __restrict__ Bt,
                                              float* __restrict__ outp) {
  constexpr int KSTEPS = MODE ? 18 : 16;
  constexpr int AKS0 = MODE ? 0 : 2;
  constexpr int KSB = MODE ? 18 : 16;
  const int tid = threadIdx.x;
  const int wave = tid >> 6, lane = tid & 63;
  const int l15 = lane & 15, lg = lane >> 4;
  const int nn0 = blockIdx.x * 128;
  const int ct0 = blockIdx.x * 8 + wave * 2;
  const int bt0 = MODE ? blockIdx.y * 4 : 0;
  const int laneoff = (lg * 16 + l15) * 8;
  f32x4 acc[2][4] = {};
#pragma unroll 2
  for (int su = 0; su < KSTEPS; ++su) {
    const f16x8 a0 = *reinterpret_cast<const f16x8*>(At + (size_t)((ct0 + 0) * 18 + AKS0 + su) * 512 + laneoff);
    const f16x8 a1 = *reinterpret_cast<const f16x8*>(At + (size_t)((ct0 + 1) * 18 + AKS0 + su) * 512 + laneoff);
#pragma unroll
    for (int bf = 0; bf < 4; ++bf) {
      const f16x8 b = *reinterpret_cast<const f16x8*>(Bt + (size_t)((bt0 + bf) * KSB + su) * 512 + laneoff);
      acc[0][bf] = __builtin_amdgcn_mfma_f32_16x16x32_f16(a0, b, acc[0][bf], 0, 0, 0);
      acc[1][bf] = __builtin_amdgcn_mfma_f32_16x16x32_f16(a1, b, acc[1][bf], 0, 0, 0);
    }
  }
  // D layout: col = lane&15 (mm), row = lg*4 + reg (c)  [m89-verified]
#pragma unroll
  for (int af = 0; af < 2; ++af)
#pragma unroll
    for (int bf = 0; bf < 4; ++bf)
#pragma unroll
      for (int rg = 0; rg < 4; ++rg) {
        const int c = nn0 + wave * 32 + af * 16 + lg * 4 + rg;
        const int mm = bt0 * 16 + bf * 16 + l15;
        if (MODE) {
          outp[(size_t)(mm >> 4) * NSTEP + (size_t)c * 16 + (mm & 15)] = acc[af][bf][rg];
        } else {
          outp[(size_t)c * 64 + mm] = acc[af][bf][rg];
        }
      }
}

// ---------------- scan matvec: row-in-registers + readlane broadcast ----------------
__device__ __forceinline__ float lane_bcast(float v, int l) {
  return __uint_as_float(__builtin_amdgcn_readlane(__float_as_uint(v), l));
}

// 4 accumulator chains: latency chain = 16 dependent FMAs instead of 32.
__device__ __forceinline__ float matvec_step(const float* __restrict__ Prow, float x,
                                             float v) {
  float a0 = v, a1 = 0.f, a2 = 0.f, a3 = 0.f;
#pragma unroll
  for (int j = 0; j < 16; ++j) {
    a0 = fmaf(Prow[j +  0], lane_bcast(x, j +  0), a0);
    a1 = fmaf(Prow[j + 16], lane_bcast(x, j + 16), a1);
    a2 = fmaf(Prow[j + 32], lane_bcast(x, j + 32), a2);
    a3 = fmaf(Prow[j + 48], lane_bcast(x, j + 48), a3);
  }
  return (a0 + a1) + (a2 + a3);
}

__global__ __launch_bounds__(64, 1) void k_scanA(const float* __restrict__ MP,
                                                 const float* __restrict__ VT,
                                                 float* __restrict__ W) {
  const int lane = threadIdx.x;
  const int b = blockIdx.x;
  const float* P = MP + 4 * 4096;   // M^16
  float Prow[64];
#pragma unroll
  for (int j = 0; j < 64; ++j) Prow[j] = P[lane * 64 + j];
  const float* vbase = VT + (size_t)b * SB * 64;
  float x = 0.f;
  float v0 = vbase[lane];
  float v1 = vbase[64 + lane];
  for (int s = 0; s < SB; ++s) {
    x = matvec_step(Prow, x, v0);
    v0 = v1;
    v1 = (s + 2 < SB) ? vbase[(size_t)(s + 2) * 64 + lane] : 0.f;
  }
  W[b * 64 + lane] = x;
}

__global__ __launch_bounds__(64, 1) void k_scanB(const float* __restrict__ MP,
                                                 const float* __restrict__ W,
                                                 float* __restrict__ XB) {
  const int lane = threadIdx.x;
  const float* Q = MP + 5 * 4096;   // M^2048
  float Qrow[64];
#pragma unroll
  for (int j = 0; j < 64; ++j) Qrow[j] = Q[lane * 64 + j];
  float x = 0.f;
  float v0 = W[lane];
  float v1 = W[64 + lane];
  for (int b = 0; b < NBLK; ++b) {
    XB[b * 64 + lane] = x;          // state at start of scan-block b
    x = matvec_step(Qrow, x, v0);
    v0 = v1;
    v1 = (b + 2 < NBLK) ? W[(b + 2) * 64 + lane] : 0.f;
  }
}

__global__ __launch_bounds__(64, 1) void k_scanC(const float* __restrict__ MP,
                                                 const float* __restrict__ VT,
                                                 const float* __restrict__ XB,
                                                 f16* __restrict__ Zt) {
  __shared__ float xt2[SB][68];     // [s][j]
  const int lane = threadIdx.x;
  const int b = blockIdx.x;
  const float* P = MP + 4 * 4096;
  float Prow[64];
#pragma unroll
  for (int j = 0; j < 64; ++j) Prow[j] = P[lane * 64 + j];
  const float* vbase = VT + (size_t)b * SB * 64;
  float x = XB[b * 64 + lane];
  float v0 = vbase[lane];
  float v1 = vbase[64 + lane];
  for (int s = 0; s < SB; ++s) {
    xt2[s][lane] = x;               // x_c BEFORE consuming v_c
    x = matvec_step(Prow, x, v0);
    v0 = v1;
    v1 = (s + 2 < SB) ? vbase[(size_t)(s + 2) * 64 + lane] : 0.f;
  }
  __syncthreads();
  // write x-part (k=0..63 → ks 0..1) of tiled Zh
#pragma unroll
  for (int h = 0; h < 2; ++h) {
    const int s = h * 64 + lane;
    const int c = b * SB + s;
    const int ct = c >> 4, l = c & 15;
#pragma unroll
    for (int ks = 0; ks < 2; ++ks)
#pragma unroll
      for (int lg = 0; lg < 4; ++lg) {
        f16x8 hv;
#pragma unroll
        for (int e = 0; e < 8; ++e) hv[e] = (f16)xt2[s][ks * 32 + lg * 8 + e];
        *reinterpret_cast<f16x8*>(Zt + ((size_t)(ct * 18 + ks) * 64 + lg * 16 + l) * 8) = hv;
      }
  }
}

extern "C" void kernel_launch(void* const* d_in, const int* in_sizes, int n_in,
                              void* d_out, int out_size, void* d_ws, size_t ws_size,
                              hipStream_t stream) {
  const float* y = (const float*)d_in[0];
  const float* A = (const float*)d_in[1];
  const float* H = (const float*)d_in[2];
  const float* L = (const float*)d_in[3];
  float* ws = (float*)d_ws;
  f16* Zt   = reinterpret_cast<f16*>(ws + OFF_ZH);
  float* VT = ws + OFF_VT;
  float* MP = ws + OFF_MP;
  f16* BOt  = reinterpret_cast<f16*>(ws + OFF_BO);
  f16* GCt  = reinterpret_cast<f16*>(ws + OFF_GC);
  float* Fb = ws + OFF_FB;
  float* Gb = ws + OFF_GB;
  float* Kd = ws + OFF_KD;
  float* W  = ws + OFF_W;
  float* XB = ws + OFF_XB;
  float* out = (float*)d_out;

  k_pack<<<dim3(CCH / 16), dim3(256), 0, stream>>>(y, Zt);
  k_p1<<<dim3(1), dim3(1024), 0, stream>>>(A, H, L, MP, Fb, Gb);
  k_fg<<<dim3(6), dim3(256), 0, stream>>>(MP, Fb, Gb, 0);
  k_fg<<<dim3(24), dim3(256), 0, stream>>>(MP, Fb, Gb, 1);
  k_kd<<<dim3(60), dim3(256), 0, stream>>>(Fb, L, Kd);
  k_asm<<<dim3(160), dim3(256), 0, stream>>>(Fb, Gb, Kd, BOt, GCt);
  // V GEMM (MFMA): VT[c][j] = sum_f Zh[c][64+f] * GCh[j][f]
  k_mfma<0><<<dim3(CCH / 128, 1), dim3(256), 0, stream>>>(Zt, GCt, VT);
  k_scanA<<<dim3(NBLK), dim3(64), 0, stream>>>(MP, VT, W);
  k_scanB<<<dim3(1), dim3(64), 0, stream>>>(MP, W, XB);
  k_scanC<<<dim3(NBLK), dim3(64), 0, stream>>>(MP, VT, XB, Zt);
  // Output GEMM (MFMA): out[i][c*16+t] = sum_k Zh[c][k] * BOh[i*16+t][k]
  k_mfma<1><<<dim3(CCH / 128, MOUT / 64), dim3(256), 0, stream>>>(Zt, BOt, out);
}

// Round 7
// 285.688 us; speedup vs baseline: 1.9855x; 1.1696x over previous
//
#include <hip/hip_runtime.h>
#include <hip/hip_bf16.h>

// Kalman recurrence, exact chunked parallelization. Round 7.
//   x[k+1] = M x[k] + L y[:,k],  M = A - L H,  yhat[:,k] = H x[k], x[0]=0
// Chunk T=16:  yhat[cT+t] = F_t x_c + sum_{s<t} K_{t-1-s} y[cT+s]
//   F_t = H M^t, K_d = H M^d L, v_c = sum_t M^{15-t} L y[cT+t]
//   x_{c+1} = P x_c + v_c, P = M^16.  3-level fp32 scan over C=16384 chunks.
// Round-7: scan kernels LDS-stage their VT/W slice up front (the serial loop was
// eating ~700 cyc/step of exposed global latency: 1000 cyc/step measured vs ~260
// issue) and take v at the END of the step so the ds_read has a full step of slack.

#define NSTEP 262144
#define T 16
#define CCH (NSTEP / T)          // 16384 chunks
#define KDIM (64 + 32 * T)       // 576
#define MOUT (32 * T)            // 512
#define NBLK 128                 // scan blocks
#define SB (CCH / NBLK)          // 128 chunks per scan block

typedef _Float16 f16;
typedef _Float16 f16x4 __attribute__((ext_vector_type(4)));
typedef _Float16 f16x8 __attribute__((ext_vector_type(8)));
typedef float f32x4 __attribute__((ext_vector_type(4)));

// Fragment-major tile layout for a [rows][K] f16 matrix:
//   slot(ct, ks, lg, l) = ((ct*KS + ks)*4 + lg)*16 + l   (one slot = 8 f16 = 16B)
//   element (r, k): ct=r>>4, l=r&15, ks=k>>5, lg=(k>>3)&3, e=k&7
// A wave's MFMA fragment load (lane = lg*16+l15) is then 64 consecutive 16B.

// ---- workspace layout (float units) ----
#define OFF_ZH 0                          // Zh tiled: CCH rows x 576 k (KS=18)
#define SZ_ZH  (CCH * KDIM / 2)
#define OFF_VT (OFF_ZH + SZ_ZH)           // VT: f32 [CCH][64]
#define SZ_VT  (CCH * 64)
#define OFF_MP (OFF_VT + SZ_VT)           // M powers: 0:M 1:M2 2:M4 3:M8 4:M16 5:M2048 6:M3 7:M12
#define SZ_MP  (8 * 4096)
#define OFF_BO (OFF_MP + SZ_MP)           // BOh tiled: 512 rows x 576 k (KS=18)
#define SZ_BO  (MOUT * KDIM / 2)
#define OFF_GC (OFF_BO + SZ_BO)           // GCh tiled: 64 rows x 512 k (KS=16)
#define SZ_GC  (64 * 512 / 2)
#define OFF_FB (OFF_GC + SZ_GC)           // Fbuf: f32 16 x (32x64)
#define SZ_FB  (16 * 2048)
#define OFF_GB (OFF_FB + SZ_FB)           // Gbuf: f32 16 x (64x32)
#define SZ_GB  (16 * 2048)
#define OFF_KD (OFF_GB + SZ_GB)           // Kd: f32 15 x (32x32)
#define SZ_KD  (15 * 1024)
#define OFF_W  (OFF_KD + SZ_KD)           // [128][64]
#define OFF_XB (OFF_W + NBLK * 64)        // [128][64]

// ---- pack: Zh[c][64+t*32+i] = (f16) y[i][c*16+t], tiled layout, 16 chunks/block ----
__global__ __launch_bounds__(256) void k_pack(const float* __restrict__ y,
                                              f16* __restrict__ Zt) {
  __shared__ f16 Lt[32][264];               // [i][local timestep 0..255], +8 pad
  const int tid = threadIdx.x;
  const int ct = blockIdx.x;                // c-tile: chunks ct*16 .. ct*16+15
  const size_t colbase = (size_t)ct * 256;  // timestep base
#pragma unroll
  for (int v = 0; v < 8; ++v) {
    const int fidx = v * 256 + tid;         // 2048 float4 over [32][256]
    const int row = fidx >> 6, col4 = fidx & 63;
    const float4 w = *reinterpret_cast<const float4*>(y + (size_t)row * NSTEP + colbase + col4 * 4);
    f16x4 h = {(f16)w.x, (f16)w.y, (f16)w.z, (f16)w.w};
    *reinterpret_cast<f16x4*>(&Lt[row][col4 * 4]) = h;
  }
  __syncthreads();
#pragma unroll
  for (int v = 0; v < 4; ++v) {
    const int s = v * 256 + tid;            // slot within block: ((t*4)+lg)*16 + l
    const int l = s & 15, lg = (s >> 4) & 3, t = s >> 6;
    f16x8 hv;
#pragma unroll
    for (int e = 0; e < 8; ++e) hv[e] = Lt[lg * 8 + e][l * 16 + t];
    *reinterpret_cast<f16x8*>(Zt + ((size_t)(ct * 18 + 2 + t) * 64 + lg * 16 + l) * 8) = hv;
  }
}

// ---- P1: M = A - L H; powers M2,M3,M4,M8,M12,M16,M2048 via LDS matmuls;
//      also seeds Fbuf[0]=H, Gbuf[0]=L ----
__global__ __launch_bounds__(1024) void k_p1(const float* __restrict__ A,
                                             const float* __restrict__ H,
                                             const float* __restrict__ L,
                                             float* __restrict__ MP,
                                             float* __restrict__ Fb,
                                             float* __restrict__ Gb) {
  __shared__ float B0[64 * 68], B1[64 * 68], B2[64 * 68];
  const int tid = threadIdx.x;
  const int i = tid >> 4;
  const int j0 = (tid & 15) << 2;

  // mm: D[i][j0..3] = sum_k X[i][k]*Y[k][j0..3]; optional LDS dst + global dst
  auto mm = [&](float* ldst, const float* X, const float* Y, float* gdst) {
    float c0 = 0.f, c1 = 0.f, c2 = 0.f, c3 = 0.f;
    for (int k = 0; k < 64; ++k) {
      const float r = X[i * 68 + k];
      const float* col = &Y[k * 68 + j0];
      c0 = fmaf(r, col[0], c0); c1 = fmaf(r, col[1], c1);
      c2 = fmaf(r, col[2], c2); c3 = fmaf(r, col[3], c3);
    }
    if (ldst) { ldst[i * 68 + j0 + 0] = c0; ldst[i * 68 + j0 + 1] = c1;
                ldst[i * 68 + j0 + 2] = c2; ldst[i * 68 + j0 + 3] = c3; }
    if (gdst) { gdst[i * 64 + j0 + 0] = c0; gdst[i * 64 + j0 + 1] = c1;
                gdst[i * 64 + j0 + 2] = c2; gdst[i * 64 + j0 + 3] = c3; }
  };

  // M = A - L H
  float a0 = A[i * 64 + j0 + 0], a1 = A[i * 64 + j0 + 1];
  float a2 = A[i * 64 + j0 + 2], a3 = A[i * 64 + j0 + 3];
  for (int q = 0; q < 32; ++q) {
    const float l = L[i * 32 + q];
    a0 -= l * H[q * 64 + j0 + 0]; a1 -= l * H[q * 64 + j0 + 1];
    a2 -= l * H[q * 64 + j0 + 2]; a3 -= l * H[q * 64 + j0 + 3];
  }
  B0[i * 68 + j0 + 0] = a0; B0[i * 68 + j0 + 1] = a1;
  B0[i * 68 + j0 + 2] = a2; B0[i * 68 + j0 + 3] = a3;
  MP[i * 64 + j0 + 0] = a0; MP[i * 64 + j0 + 1] = a1;
  MP[i * 64 + j0 + 2] = a2; MP[i * 64 + j0 + 3] = a3;
  for (int e = tid; e < 2048; e += 1024) { Fb[e] = H[e]; Gb[e] = L[e]; }
  __syncthreads();

  mm(B1, B0, B0, MP + 1 * 4096); __syncthreads();   // M2
  mm(nullptr, B1, B0, MP + 6 * 4096); __syncthreads(); // M3 = M2*M
  mm(B2, B1, B1, MP + 2 * 4096); __syncthreads();   // M4
  mm(B0, B2, B2, MP + 3 * 4096); __syncthreads();   // M8 (overwrites M)
  mm(nullptr, B2, B0, MP + 7 * 4096); __syncthreads(); // M12 = M4*M8
  mm(B1, B0, B0, MP + 4 * 4096); __syncthreads();   // M16
  float* cur = B1; float* oth = B2;
  for (int s2 = 0; s2 < 7; ++s2) {                  // M32..M2048
    mm(oth, cur, cur, (s2 == 6) ? MP + 5 * 4096 : nullptr);
    __syncthreads();
    float* tmp = cur; cur = oth; oth = tmp;
  }
}

// ---- FG: F_{dst} = F_{src} * M^p  /  G_{dst} = M^p * G_{src}; 1 matmul/block ----
__global__ __launch_bounds__(256) void k_fg(const float* __restrict__ MP,
                                            float* __restrict__ Fb,
                                            float* __restrict__ Gb,
                                            const int phase) {
  const int tid = threadIdx.x;
  const int nHalf = phase ? 12 : 3;
  const int half = blockIdx.x / nHalf, r = blockIdx.x % nHalf;
  int src, dst, msl;
  if (phase == 0) { src = 0; dst = r + 1; msl = (r == 0) ? 0 : (r == 1) ? 1 : 6; }
  else { const int b = r / 4 + 1, s = r % 4; src = s; dst = 4 * b + s;
         msl = (b == 1) ? 2 : (b == 2) ? 3 : 7; }
  const float* __restrict__ Mx = MP + msl * 4096;
  if (half == 0) {
    const int j = tid & 63, ih = tid >> 6;
    const float* Fs = Fb + src * 2048;
    float* Fd = Fb + dst * 2048;
#pragma unroll
    for (int u = 0; u < 8; ++u) {
      const int i = ih * 8 + u;
      float acc = 0.f;
#pragma unroll 8
      for (int q = 0; q < 64; ++q) acc = fmaf(Fs[i * 64 + q], Mx[q * 64 + j], acc);
      Fd[i * 64 + j] = acc;
    }
  } else {
    const int q = tid & 31, ih = tid >> 5;
    const float* Gs = Gb + src * 2048;
    float* Gd = Gb + dst * 2048;
#pragma unroll
    for (int u = 0; u < 8; ++u) {
      const int i = ih * 8 + u;
      float acc = 0.f;
#pragma unroll 8
      for (int p = 0; p < 64; ++p) acc = fmaf(Mx[i * 64 + p], Gs[p * 32 + q], acc);
      Gd[i * 32 + q] = acc;
    }
  }
}

// ---- KD: K_d = F_d * L (15 x 32x32) ----
__global__ __launch_bounds__(256) void k_kd(const float* __restrict__ Fb,
                                            const float* __restrict__ L,
                                            float* __restrict__ Kd) {
  const int o = blockIdx.x * 256 + threadIdx.x;   // < 15360
  const int d = o >> 10, i = (o >> 5) & 31, q = o & 31;
  float acc = 0.f;
#pragma unroll 8
  for (int j = 0; j < 64; ++j) acc = fmaf(Fb[d * 2048 + i * 64 + j], L[j * 32 + q], acc);
  Kd[o] = acc;
}

// ---- ASM: assemble BOh (tiled f16) and GCh (tiled f16) ----
__global__ __launch_bounds__(256) void k_asm(const float* __restrict__ Fb,
                                             const float* __restrict__ Gb,
                                             const float* __restrict__ Kd,
                                             f16* __restrict__ BOt,
                                             f16* __restrict__ GCt) {
  const int sid = blockIdx.x * 256 + threadIdx.x;
  if (sid < 512 * 72) {            // BOh: 32 mt x 18 ks x 4 lg x 16 l slots
    const int l = sid & 15, lg = (sid >> 4) & 3;
    const int t18 = sid >> 6;
    const int mt = t18 / 18, ks = t18 - mt * 18;
    const int i = mt, t = l;
    const int k0 = ks * 32 + lg * 8;
    f16x8 hv;
    if (k0 + 7 < 64) {
#pragma unroll
      for (int e = 0; e < 8; ++e) hv[e] = (f16)Fb[t * 2048 + i * 64 + k0 + e];
    } else {
      const int kk = k0 - 64;
      const int s = kk >> 5, q0 = kk & 31;
      if (s < t) {
        const int d = t - 1 - s;
#pragma unroll
        for (int e = 0; e < 8; ++e) hv[e] = (f16)Kd[d * 1024 + i * 32 + q0 + e];
      } else {
#pragma unroll
        for (int e = 0; e < 8; ++e) hv[e] = (f16)0.f;
      }
    }
    *reinterpret_cast<f16x8*>(BOt + (size_t)sid * 8) = hv;
  } else {                          // GCh: 4 jt x 16 ks x 4 lg x 16 l slots
    const int sid2 = sid - 512 * 72;
    if (sid2 < 4096) {
      const int l = sid2 & 15, lg = (sid2 >> 4) & 3;
      const int t16 = sid2 >> 6;
      const int jt = t16 >> 4, ks = t16 & 15;
      const int j = jt * 16 + l;
      const int ii = lg * 8;
      f16x8 hv;
#pragma unroll
      for (int e = 0; e < 8; ++e) hv[e] = (f16)Gb[(15 - ks) * 2048 + j * 32 + ii + e];
      *reinterpret_cast<f16x8*>(GCt + (size_t)sid2 * 8) = hv;
    }
  }
}

// ---- f16 MFMA GEMM on tiled operands. C[c][mm] = sum_k Zh[c][k]*B[mm][k].
//      MODE 0: B=GCh (KS_B=16, A ks 2..17), out VT[c][64]
//      MODE 1: B=BOh (KS_B=18, A ks 0..17), out d_out[i*NSTEP + c*16 + t] ----
template <int MODE>
__global__ __launch_bounds__(256) void k_mfma(const f16* __restrict__ At,
                                              const f16* __restrict__ Bt,
                                              float* __restrict__ outp) {
  constexpr int KSTEPS = MODE ? 18 : 16;
  constexpr int AKS0 = MODE ? 0 : 2;
  constexpr int KSB = MODE ? 18 : 16;
  const int tid = threadIdx.x;
  const int wave = tid >> 6, lane = tid & 63;
  const int l15 = lane & 15, lg = lane >> 4;
  const int nn0 = blockIdx.x * 128;
  const int ct0 = blockIdx.x * 8 + wave * 2;
  const int bt0 = MODE ? blockIdx.y * 4 : 0;
  const int laneoff = (lg * 16 + l15) * 8;
  f32x4 acc[2][4] = {};
#pragma unroll 2
  for (int su = 0; su < KSTEPS; ++su) {
    const f16x8 a0 = *reinterpret_cast<const f16x8*>(At + (size_t)((ct0 + 0) * 18 + AKS0 + su) * 512 + laneoff);
    const f16x8 a1 = *reinterpret_cast<const f16x8*>(At + (size_t)((ct0 + 1) * 18 + AKS0 + su) * 512 + laneoff);
#pragma unroll
    for (int bf = 0; bf < 4; ++bf) {
      const f16x8 b = *reinterpret_cast<const f16x8*>(Bt + (size_t)((bt0 + bf) * KSB + su) * 512 + laneoff);
      acc[0][bf] = __builtin_amdgcn_mfma_f32_16x16x32_f16(a0, b, acc[0][bf], 0, 0, 0);
      acc[1][bf] = __builtin_amdgcn_mfma_f32_16x16x32_f16(a1, b, acc[1][bf], 0, 0, 0);
    }
  }
  // D layout: col = lane&15 (mm), row = lg*4 + reg (c)  [m89-verified]
#pragma unroll
  for (int af = 0; af < 2; ++af)
#pragma unroll
    for (int bf = 0; bf < 4; ++bf)
#pragma unroll
      for (int rg = 0; rg < 4; ++rg) {
        const int c = nn0 + wave * 32 + af * 16 + lg * 4 + rg;
        const int mm = bt0 * 16 + bf * 16 + l15;
        if (MODE) {
          outp[(size_t)(mm >> 4) * NSTEP + (size_t)c * 16 + (mm & 15)] = acc[af][bf][rg];
        } else {
          outp[(size_t)c * 64 + mm] = acc[af][bf][rg];
        }
      }
}

// ---------------- scan matvec: row-in-registers + readlane broadcast ----------------
__device__ __forceinline__ float lane_bcast(float v, int l) {
  return __uint_as_float(__builtin_amdgcn_readlane(__float_as_uint(v), l));
}

// 4 accumulator chains; v is added at the END (ds_read gets a full step of slack).
__device__ __forceinline__ float matvec_dot(const float* __restrict__ Prow, float x) {
  float a0 = 0.f, a1 = 0.f, a2 = 0.f, a3 = 0.f;
#pragma unroll
  for (int j = 0; j < 16; ++j) {
    a0 = fmaf(Prow[j +  0], lane_bcast(x, j +  0), a0);
    a1 = fmaf(Prow[j + 16], lane_bcast(x, j + 16), a1);
    a2 = fmaf(Prow[j + 32], lane_bcast(x, j + 32), a2);
    a3 = fmaf(Prow[j + 48], lane_bcast(x, j + 48), a3);
  }
  return (a0 + a1) + (a2 + a3);
}

// stage `n` floats from g into lds (64 lanes, float4, 8 loads in flight)
__device__ __forceinline__ void stage_lds(const float* __restrict__ g,
                                          float* __restrict__ lds,
                                          int n, int lane) {
  const int iters = n >> 8;                  // 256 floats per iter
  for (int r = 0; r < iters; r += 8) {
    float4 tmp[8];
#pragma unroll
    for (int u = 0; u < 8; ++u)
      tmp[u] = *reinterpret_cast<const float4*>(g + (size_t)(r + u) * 256 + lane * 4);
#pragma unroll
    for (int u = 0; u < 8; ++u)
      *reinterpret_cast<float4*>(lds + (size_t)(r + u) * 256 + lane * 4) = tmp[u];
  }
}

__global__ __launch_bounds__(64, 1) void k_scanA(const float* __restrict__ MP,
                                                 const float* __restrict__ VT,
                                                 float* __restrict__ W) {
  __shared__ float SV[SB * 64];     // 32 KiB: this block's VT slice
  const int lane = threadIdx.x;
  const int b = blockIdx.x;
  stage_lds(VT + (size_t)b * SB * 64, SV, SB * 64, lane);
  const float* P = MP + 4 * 4096;   // M^16
  float Prow[64];
#pragma unroll
  for (int j = 0; j < 64; ++j) Prow[j] = P[lane * 64 + j];
  __syncthreads();
  float x = 0.f;
  for (int s = 0; s < SB; ++s) {
    const float v = SV[s * 64 + lane];
    x = matvec_dot(Prow, x) + v;
  }
  W[b * 64 + lane] = x;
}

__global__ __launch_bounds__(64, 1) void k_scanB(const float* __restrict__ MP,
                                                 const float* __restrict__ W,
                                                 float* __restrict__ XB) {
  __shared__ float SW[NBLK * 64];   // 32 KiB
  const int lane = threadIdx.x;
  stage_lds(W, SW, NBLK * 64, lane);
  const float* Q = MP + 5 * 4096;   // M^2048
  float Qrow[64];
#pragma unroll
  for (int j = 0; j < 64; ++j) Qrow[j] = Q[lane * 64 + j];
  __syncthreads();
  float x = 0.f;
  for (int b = 0; b < NBLK; ++b) {
    XB[b * 64 + lane] = x;          // state at start of scan-block b
    const float v = SW[b * 64 + lane];
    x = matvec_dot(Qrow, x) + v;
  }
}

__global__ __launch_bounds__(64, 1) void k_scanC(const float* __restrict__ MP,
                                                 const float* __restrict__ VT,
                                                 const float* __restrict__ XB,
                                                 f16* __restrict__ Zt) {
  __shared__ float SV[SB * 64];     // 32 KiB
  __shared__ float xt2[SB][68];     // 34 KiB  [s][j]
  const int lane = threadIdx.x;
  const int b = blockIdx.x;
  stage_lds(VT + (size_t)b * SB * 64, SV, SB * 64, lane);
  const float* P = MP + 4 * 4096;
  float Prow[64];
#pragma unroll
  for (int j = 0; j < 64; ++j) Prow[j] = P[lane * 64 + j];
  float x = XB[b * 64 + lane];
  __syncthreads();
  for (int s = 0; s < SB; ++s) {
    xt2[s][lane] = x;               // x_c BEFORE consuming v_c
    const float v = SV[s * 64 + lane];
    x = matvec_dot(Prow, x) + v;
  }
  __syncthreads();
  // write x-part (k=0..63 → ks 0..1) of tiled Zh
#pragma unroll
  for (int h = 0; h < 2; ++h) {
    const int s = h * 64 + lane;
    const int c = b * SB + s;
    const int ct = c >> 4, l = c & 15;
#pragma unroll
    for (int ks = 0; ks < 2; ++ks)
#pragma unroll
      for (int lg = 0; lg < 4; ++lg) {
        f16x8 hv;
#pragma unroll
        for (int e = 0; e < 8; ++e) hv[e] = (f16)xt2[s][ks * 32 + lg * 8 + e];
        *reinterpret_cast<f16x8*>(Zt + ((size_t)(ct * 18 + ks) * 64 + lg * 16 + l) * 8) = hv;
      }
  }
}

extern "C" void kernel_launch(void* const* d_in, const int* in_sizes, int n_in,
                              void* d_out, int out_size, void* d_ws, size_t ws_size,
                              hipStream_t stream) {
  const float* y = (const float*)d_in[0];
  const float* A = (const float*)d_in[1];
  const float* H = (const float*)d_in[2];
  const float* L = (const float*)d_in[3];
  float* ws = (float*)d_ws;
  f16* Zt   = reinterpret_cast<f16*>(ws + OFF_ZH);
  float* VT = ws + OFF_VT;
  float* MP = ws + OFF_MP;
  f16* BOt  = reinterpret_cast<f16*>(ws + OFF_BO);
  f16* GCt  = reinterpret_cast<f16*>(ws + OFF_GC);
  float* Fb = ws + OFF_FB;
  float* Gb = ws + OFF_GB;
  float* Kd = ws + OFF_KD;
  float* W  = ws + OFF_W;
  float* XB = ws + OFF_XB;
  float* out = (float*)d_out;

  k_pack<<<dim3(CCH / 16), dim3(256), 0, stream>>>(y, Zt);
  k_p1<<<dim3(1), dim3(1024), 0, stream>>>(A, H, L, MP, Fb, Gb);
  k_fg<<<dim3(6), dim3(256), 0, stream>>>(MP, Fb, Gb, 0);
  k_fg<<<dim3(24), dim3(256), 0, stream>>>(MP, Fb, Gb, 1);
  k_kd<<<dim3(60), dim3(256), 0, stream>>>(Fb, L, Kd);
  k_asm<<<dim3(160), dim3(256), 0, stream>>>(Fb, Gb, Kd, BOt, GCt);
  // V GEMM (MFMA): VT[c][j] = sum_f Zh[c][64+f] * GCh[j][f]
  k_mfma<0><<<dim3(CCH / 128, 1), dim3(256), 0, stream>>>(Zt, GCt, VT);
  k_scanA<<<dim3(NBLK), dim3(64), 0, stream>>>(MP, VT, W);
  k_scanB<<<dim3(1), dim3(64), 0, stream>>>(MP, W, XB);
  k_scanC<<<dim3(NBLK), dim3(64), 0, stream>>>(MP, VT, XB, Zt);
  // Output GEMM (MFMA): out[i][c*16+t] = sum_k Zh[c][k] * BOh[i*16+t][k]
  k_mfma<1><<<dim3(CCH / 128, MOUT / 64), dim3(256), 0, stream>>>(Zt, BOt, out);
}